// Round 1
// baseline (12684.319 us; speedup 1.0000x reference)
//
#include <hip/hip_runtime.h>
#include <math.h>

#define N 1024
#define D 512
#define NIT 200
#define PIT 50

// ---------------- helpers ----------------
__device__ __forceinline__ float wave_reduce(float v) {
#pragma unroll
  for (int off = 32; off; off >>= 1) v += __shfl_xor(v, off, 64);
  return v;
}

// ---------------- row normalize (both inputs in one grid) ----------------
__global__ __launch_bounds__(256) void normalize_k(
    const float* __restrict__ f1, const float* __restrict__ f2,
    float* __restrict__ Yn, float* __restrict__ An) {
  int b = blockIdx.x;
  const float* src;
  float* dst;
  if (b < N) { src = f1 + (size_t)b * D; dst = Yn + (size_t)b * D; }
  else       { src = f2 + (size_t)(b - N) * D; dst = An + (size_t)(b - N) * D; }
  int tid = threadIdx.x;
  float2 e = ((const float2*)src)[tid];
  float ss = e.x * e.x + e.y * e.y;
  ss = wave_reduce(ss);
  __shared__ float sh[4];
  int lane = tid & 63, wid = tid >> 6;
  if (lane == 0) sh[wid] = ss;
  __syncthreads();
  float total = sh[0] + sh[1] + sh[2] + sh[3];
  float rn = 1.0f / sqrtf(total);
  ((float2*)dst)[tid] = make_float2(e.x * rn, e.y * rn);
}

// ---------------- fp32 NT GEMM: C[i][j] = sum_k A[i][k]*B[j][k] ----------------
// mode 0: C = acc
// mode 1: C = Z - 2*step*(acc - Yp)   (FISTA pre-projection point)
#define BM 64
#define BN 64
#define BK 32
#define LDT 68  // padded LDS stride (68*4 bytes = 272 = 16*17, keeps b128 alignment)

__global__ __launch_bounds__(256) void gemm_nt(
    const float* __restrict__ A, int lda,
    const float* __restrict__ B, int ldb,
    float* __restrict__ C, int ldc, int K, int mode,
    const float* __restrict__ Zp, const float* __restrict__ Yp,
    const float* __restrict__ stepPtr) {
  __shared__ __align__(16) float At[BK][LDT];  // At[k][m]
  __shared__ __align__(16) float Bt[BK][LDT];  // Bt[k][n]
  const int tid = threadIdx.x;
  const int rowBase = blockIdx.y * BM;
  const int colBase = blockIdx.x * BN;
  const int tx = tid & 15, ty = tid >> 4;
  float acc[4][4] = {};
  const int r0 = tid >> 3;       // rows 0..31
  const int r1 = r0 + 32;        // rows 32..63
  const int kc = (tid & 7) * 4;  // k-offset 0..28

  for (int k0 = 0; k0 < K; k0 += BK) {
    __syncthreads();
    {
      float4 av = *(const float4*)(A + (size_t)(rowBase + r0) * lda + k0 + kc);
      At[kc + 0][r0] = av.x; At[kc + 1][r0] = av.y; At[kc + 2][r0] = av.z; At[kc + 3][r0] = av.w;
      float4 bv = *(const float4*)(B + (size_t)(colBase + r0) * ldb + k0 + kc);
      Bt[kc + 0][r0] = bv.x; Bt[kc + 1][r0] = bv.y; Bt[kc + 2][r0] = bv.z; Bt[kc + 3][r0] = bv.w;
      av = *(const float4*)(A + (size_t)(rowBase + r1) * lda + k0 + kc);
      At[kc + 0][r1] = av.x; At[kc + 1][r1] = av.y; At[kc + 2][r1] = av.z; At[kc + 3][r1] = av.w;
      bv = *(const float4*)(B + (size_t)(colBase + r1) * ldb + k0 + kc);
      Bt[kc + 0][r1] = bv.x; Bt[kc + 1][r1] = bv.y; Bt[kc + 2][r1] = bv.z; Bt[kc + 3][r1] = bv.w;
    }
    __syncthreads();
#pragma unroll
    for (int kk = 0; kk < BK; ++kk) {
      float4 a4 = *(const float4*)&At[kk][ty * 4];
      float4 b4 = *(const float4*)&Bt[kk][tx * 4];
      float a[4] = {a4.x, a4.y, a4.z, a4.w};
      float b[4] = {b4.x, b4.y, b4.z, b4.w};
#pragma unroll
      for (int r = 0; r < 4; ++r)
#pragma unroll
        for (int c = 0; c < 4; ++c) acc[r][c] = fmaf(a[r], b[c], acc[r][c]);
    }
  }

  float c2 = 0.0f;
  if (mode == 1) c2 = 2.0f * stepPtr[0];
#pragma unroll
  for (int r = 0; r < 4; ++r) {
    int i = rowBase + ty * 4 + r;
    size_t off = (size_t)i * ldc + colBase + tx * 4;
    float4 o;
    if (mode == 1) {
      float4 z = *(const float4*)(Zp + off);
      float4 y = *(const float4*)(Yp + off);
      o.x = z.x - c2 * (acc[r][0] - y.x);
      o.y = z.y - c2 * (acc[r][1] - y.y);
      o.z = z.z - c2 * (acc[r][2] - y.z);
      o.w = z.w - c2 * (acc[r][3] - y.w);
    } else {
      o = make_float4(acc[r][0], acc[r][1], acc[r][2], acc[r][3]);
    }
    *(float4*)(C + off) = o;
  }
}

// ---------------- matvec: w = scale * (M v), one wave per row ----------------
__global__ __launch_bounds__(256) void matvec_k(
    const float* __restrict__ Mm, const float* __restrict__ v,
    float* __restrict__ w, float scale) {
  int tid = threadIdx.x;
  int lane = tid & 63, wid = tid >> 6;
  int row = blockIdx.x * 4 + wid;
  const float* mr = Mm + (size_t)row * N;
  float s = 0.0f;
#pragma unroll
  for (int j = 0; j < N; j += 64) s = fmaf(mr[j + lane], v[j + lane], s);
  s = wave_reduce(s);
  if (lane == 0) w[row] = s * scale;
}

// ---------------- Rayleigh quotient -> step = 1/(2*u.Mu/u.u + eps) ----------------
__global__ __launch_bounds__(256) void rayleigh_k(
    const float* __restrict__ u, const float* __restrict__ w,
    float* __restrict__ stepOut) {
  int tid = threadIdx.x;
  float r1 = 0.0f, r2 = 0.0f;
  for (int j = tid; j < N; j += 256) {
    float uu = u[j];
    r1 = fmaf(uu, w[j], r1);
    r2 = fmaf(uu, uu, r2);
  }
  r1 = wave_reduce(r1);
  r2 = wave_reduce(r2);
  __shared__ float sh[8];
  int lane = tid & 63, wid = tid >> 6;
  if (lane == 0) { sh[wid] = r1; sh[4 + wid] = r2; }
  __syncthreads();
  if (tid == 0) {
    float R1 = sh[0] + sh[1] + sh[2] + sh[3];
    float R2 = sh[4] + sh[5] + sh[6] + sh[7];
    float L = 2.0f * (R1 / R2);
    stepOut[0] = 1.0f / (L + 1e-8f);
  }
}

// ---------------- init X = Z = 1/n, v = 1/n ----------------
__global__ __launch_bounds__(256) void init_k(float* __restrict__ X,
                                              float* __restrict__ Z,
                                              float* __restrict__ v) {
  int i = blockIdx.x * 256 + threadIdx.x;
  const float c = 1.0f / (float)N;
  X[i] = c;
  Z[i] = c;
  if (i < N) v[i] = c;
}

// ---------------- per-row simplex projection (Michelot) + FISTA update ----------------
__global__ __launch_bounds__(256) void fista_update_k(
    const float* __restrict__ V, float* __restrict__ X, float* __restrict__ Z,
    float mom) {
  __shared__ float sh[8];
  const int r = blockIdx.x, tid = threadIdx.x;
  const int lane = tid & 63, wid = tid >> 6;
  float4 v4 = ((const float4*)(V + (size_t)r * N))[tid];
  float vl[4] = {v4.x, v4.y, v4.z, v4.w};
  float s = vl[0] + vl[1] + vl[2] + vl[3];
  s = wave_reduce(s);
  if (lane == 0) sh[wid] = s;
  __syncthreads();
  float theta = (sh[0] + sh[1] + sh[2] + sh[3] - 1.0f) * (1.0f / (float)N);
  // Michelot: theta increases monotonically to the exact projection threshold
  for (int it = 0; it < 40; ++it) {
    float sa = 0.0f, ka = 0.0f;
#pragma unroll
    for (int j = 0; j < 4; ++j)
      if (vl[j] > theta) { sa += vl[j]; ka += 1.0f; }
    sa = wave_reduce(sa);
    ka = wave_reduce(ka);
    __syncthreads();
    if (lane == 0) { sh[wid] = sa; sh[4 + wid] = ka; }
    __syncthreads();
    float SA = sh[0] + sh[1] + sh[2] + sh[3];
    float KA = fmaxf(sh[4] + sh[5] + sh[6] + sh[7], 1.0f);
    float tn = (SA - 1.0f) / KA;
    bool done = (tn - theta) <= (1e-7f * fabsf(tn) + 1e-12f);  // block-uniform
    theta = tn;
    if (done) break;
  }
  float4 x4 = ((const float4*)(X + (size_t)r * N))[tid];
  float xo[4] = {x4.x, x4.y, x4.z, x4.w};
  float xn[4], zn[4];
#pragma unroll
  for (int j = 0; j < 4; ++j) {
    xn[j] = fmaxf(vl[j] - theta, 0.0f);
    zn[j] = xn[j] + mom * (xn[j] - xo[j]);
  }
  ((float4*)(X + (size_t)r * N))[tid] = make_float4(xn[0], xn[1], xn[2], xn[3]);
  ((float4*)(Z + (size_t)r * N))[tid] = make_float4(zn[0], zn[1], zn[2], zn[3]);
}

// ---------------- transpose An [N x D] -> AnT [D x N] ----------------
__global__ void transpose_k(const float* __restrict__ An, float* __restrict__ AnT) {
  __shared__ float t[32][33];
  int x = blockIdx.x * 32 + threadIdx.x;  // col of An
  int y0 = blockIdx.y * 32;               // row of An
#pragma unroll
  for (int j = 0; j < 32; j += 8)
    t[threadIdx.y + j][threadIdx.x] = An[(size_t)(y0 + threadIdx.y + j) * D + x];
  __syncthreads();
  int xo = y0 + threadIdx.x;
  int yo0 = blockIdx.x * 32;
#pragma unroll
  for (int j = 0; j < 32; j += 8)
    AnT[(size_t)(yo0 + threadIdx.y + j) * N + xo] = t[threadIdx.x][threadIdx.y + j];
}

// ---------------- per-row cosine ----------------
__global__ __launch_bounds__(128) void cos_k(const float* __restrict__ P,
                                             const float* __restrict__ Yn,
                                             float* __restrict__ cb) {
  int r = blockIdx.x, tid = threadIdx.x;
  float4 p = ((const float4*)(P + (size_t)r * D))[tid];
  float4 y = ((const float4*)(Yn + (size_t)r * D))[tid];
  float d  = p.x * y.x + p.y * y.y + p.z * y.z + p.w * y.w;
  float np = p.x * p.x + p.y * p.y + p.z * p.z + p.w * p.w;
  float ny = y.x * y.x + y.y * y.y + y.z * y.z + y.w * y.w;
  d = wave_reduce(d);
  np = wave_reduce(np);
  ny = wave_reduce(ny);
  __shared__ float sh[6];
  int lane = tid & 63, wid = tid >> 6;
  if (lane == 0) { sh[wid] = d; sh[2 + wid] = np; sh[4 + wid] = ny; }
  __syncthreads();
  if (tid == 0) {
    float dt = sh[0] + sh[1], npt = sh[2] + sh[3], nyt = sh[4] + sh[5];
    cb[r] = dt / (fmaxf(sqrtf(npt), 1e-8f) * fmaxf(sqrtf(nyt), 1e-8f));
  }
}

// ---------------- mean over 1024 ----------------
__global__ __launch_bounds__(256) void mean_k(const float* __restrict__ cb,
                                              float* __restrict__ out) {
  int tid = threadIdx.x;
  float s = cb[tid] + cb[tid + 256] + cb[tid + 512] + cb[tid + 768];
  s = wave_reduce(s);
  __shared__ float sh[4];
  int lane = tid & 63, wid = tid >> 6;
  if (lane == 0) sh[wid] = s;
  __syncthreads();
  if (tid == 0) out[0] = (sh[0] + sh[1] + sh[2] + sh[3]) * (1.0f / (float)N);
}

// ---------------- host orchestration ----------------
extern "C" void kernel_launch(void* const* d_in, const int* in_sizes, int n_in,
                              void* d_out, int out_size, void* d_ws, size_t ws_size,
                              hipStream_t stream) {
  const float* fea1 = (const float*)d_in[0];
  const float* fea2 = (const float*)d_in[1];
  float* ws = (float*)d_ws;
  // layout (floats): Yn, An [N*D each]; Mm, YAt, X, Z, V [N*N each]; small tail
  float* Yn  = ws;
  float* An  = Yn + (size_t)N * D;
  float* Mm  = An + (size_t)N * D;
  float* YAt = Mm + (size_t)N * N;
  float* X   = YAt + (size_t)N * N;
  float* Z   = X + (size_t)N * N;
  float* V   = Z + (size_t)N * N;
  float* vp  = V + (size_t)N * N;
  float* wp  = vp + N;
  float* stepP = wp + N;
  // dead-buffer reuse after the FISTA loop:
  float* AnT = V;                       // V dead after loop
  float* P   = V + (size_t)N * D;       // second half of V's space
  float* cosb = Mm;                     // M dead after loop

  normalize_k<<<2 * N, 256, 0, stream>>>(fea1, fea2, Yn, An);
  gemm_nt<<<dim3(N / 64, N / 64), 256, 0, stream>>>(An, D, An, D, Mm, N, D, 0,
                                                    nullptr, nullptr, nullptr);
  gemm_nt<<<dim3(N / 64, N / 64), 256, 0, stream>>>(Yn, D, An, D, YAt, N, D, 0,
                                                    nullptr, nullptr, nullptr);
  init_k<<<(N * N) / 256, 256, 0, stream>>>(X, Z, vp);

  // power iteration: fold per-step normalization into a 1/8 scale (lambda_max ~ 5.8 < 8)
  float* pv = vp;
  float* pw = wp;
  for (int i = 0; i < PIT; ++i) {
    matvec_k<<<N / 4, 256, 0, stream>>>(Mm, pv, pw, 0.125f);
    float* t = pv; pv = pw; pw = t;
  }
  matvec_k<<<N / 4, 256, 0, stream>>>(Mm, pv, pw, 1.0f);
  rayleigh_k<<<1, 256, 0, stream>>>(pv, pw, stepP);

  float t = 1.0f;
  for (int it = 0; it < NIT; ++it) {
    gemm_nt<<<dim3(N / 64, N / 64), 256, 0, stream>>>(Z, N, Mm, N, V, N, N, 1,
                                                      Z, YAt, stepP);
    float tn = 0.5f * (1.0f + sqrtf(1.0f + 4.0f * t * t));
    float mom = (t - 1.0f) / tn;
    t = tn;
    fista_update_k<<<N, 256, 0, stream>>>(V, X, Z, mom);
  }

  transpose_k<<<dim3(D / 32, N / 32), dim3(32, 8), 0, stream>>>(An, AnT);
  gemm_nt<<<dim3(D / 64, N / 64), 256, 0, stream>>>(X, N, AnT, N, P, D, N, 0,
                                                    nullptr, nullptr, nullptr);
  cos_k<<<N, 128, 0, stream>>>(P, Yn, cosb);
  mean_k<<<1, 256, 0, stream>>>(cosb, (float*)d_out);
}

// Round 2
// 5984.225 us; speedup vs baseline: 2.1196x; 2.1196x over previous
//
#include <hip/hip_runtime.h>
#include <math.h>

#define N 1024
#define D 512
#define NIT 200
#define PIT 50

typedef __attribute__((ext_vector_type(8))) short short8;
typedef __attribute__((ext_vector_type(4))) float floatx4;

// ---------------- helpers ----------------
__device__ __forceinline__ float wave_reduce(float v) {
#pragma unroll
  for (int off = 32; off; off >>= 1) v += __shfl_xor(v, off, 64);
  return v;
}

__device__ __forceinline__ unsigned short f2bf(float x) {
  unsigned int u = __float_as_uint(x);
  u += 0x7FFF + ((u >> 16) & 1);  // round-to-nearest-even
  return (unsigned short)(u >> 16);
}
__device__ __forceinline__ float bf2f(unsigned short h) {
  return __uint_as_float(((unsigned int)h) << 16);
}

// async global->LDS, 16 B per lane; LDS dest must be lane-contiguous
#define GLD16(g, l)                                                     \
  __builtin_amdgcn_global_load_lds(                                     \
      (__attribute__((address_space(1))) void*)(g),                     \
      (__attribute__((address_space(3))) void*)(l), 16, 0, 0)

// ---------------- row normalize ----------------
__global__ __launch_bounds__(256) void normalize_k(
    const float* __restrict__ f1, const float* __restrict__ f2,
    float* __restrict__ Yn, float* __restrict__ An) {
  int b = blockIdx.x;
  const float* src;
  float* dst;
  if (b < N) { src = f1 + (size_t)b * D; dst = Yn + (size_t)b * D; }
  else       { src = f2 + (size_t)(b - N) * D; dst = An + (size_t)(b - N) * D; }
  int tid = threadIdx.x;
  float2 e = ((const float2*)src)[tid];
  float ss = e.x * e.x + e.y * e.y;
  ss = wave_reduce(ss);
  __shared__ float sh[4];
  int lane = tid & 63, wid = tid >> 6;
  if (lane == 0) sh[wid] = ss;
  __syncthreads();
  float total = sh[0] + sh[1] + sh[2] + sh[3];
  float rn = 1.0f / sqrtf(total);
  ((float2*)dst)[tid] = make_float2(e.x * rn, e.y * rn);
}

// ---------------- fp32 NT GEMM (one-time uses: M, YAt, final P) ----------------
#define LDT 68
__global__ __launch_bounds__(256) void gemm_nt(
    const float* __restrict__ A, int lda,
    const float* __restrict__ B, int ldb,
    float* __restrict__ C, int ldc, int K) {
  __shared__ __align__(16) float At[32][LDT];
  __shared__ __align__(16) float Bt[32][LDT];
  const int tid = threadIdx.x;
  const int rowBase = blockIdx.y * 64;
  const int colBase = blockIdx.x * 64;
  const int tx = tid & 15, ty = tid >> 4;
  float acc[4][4] = {};
  const int r0 = tid >> 3;
  const int r1 = r0 + 32;
  const int kc = (tid & 7) * 4;

  for (int k0 = 0; k0 < K; k0 += 32) {
    __syncthreads();
    {
      float4 av = *(const float4*)(A + (size_t)(rowBase + r0) * lda + k0 + kc);
      At[kc + 0][r0] = av.x; At[kc + 1][r0] = av.y; At[kc + 2][r0] = av.z; At[kc + 3][r0] = av.w;
      float4 bv = *(const float4*)(B + (size_t)(colBase + r0) * ldb + k0 + kc);
      Bt[kc + 0][r0] = bv.x; Bt[kc + 1][r0] = bv.y; Bt[kc + 2][r0] = bv.z; Bt[kc + 3][r0] = bv.w;
      av = *(const float4*)(A + (size_t)(rowBase + r1) * lda + k0 + kc);
      At[kc + 0][r1] = av.x; At[kc + 1][r1] = av.y; At[kc + 2][r1] = av.z; At[kc + 3][r1] = av.w;
      bv = *(const float4*)(B + (size_t)(colBase + r1) * ldb + k0 + kc);
      Bt[kc + 0][r1] = bv.x; Bt[kc + 1][r1] = bv.y; Bt[kc + 2][r1] = bv.z; Bt[kc + 3][r1] = bv.w;
    }
    __syncthreads();
#pragma unroll
    for (int kk = 0; kk < 32; ++kk) {
      float4 a4 = *(const float4*)&At[kk][ty * 4];
      float4 b4 = *(const float4*)&Bt[kk][tx * 4];
      float a[4] = {a4.x, a4.y, a4.z, a4.w};
      float b[4] = {b4.x, b4.y, b4.z, b4.w};
#pragma unroll
      for (int r = 0; r < 4; ++r)
#pragma unroll
        for (int c = 0; c < 4; ++c) acc[r][c] = fmaf(a[r], b[c], acc[r][c]);
    }
  }
#pragma unroll
  for (int r = 0; r < 4; ++r) {
    int i = rowBase + ty * 4 + r;
    size_t off = (size_t)i * ldc + colBase + tx * 4;
    *(float4*)(C + off) = make_float4(acc[r][0], acc[r][1], acc[r][2], acc[r][3]);
  }
}

// ---------------- split fp32 -> bf16 hi/lo ----------------
__global__ __launch_bounds__(256) void split_k(const float* __restrict__ Mm,
                                               unsigned short* __restrict__ Mh,
                                               unsigned short* __restrict__ Ml) {
  int i = blockIdx.x * 256 + threadIdx.x;
  float x = Mm[i];
  unsigned short h = f2bf(x);
  Mh[i] = h;
  Ml[i] = f2bf(x - bf2f(h));
}

// ---------------- FISTA GEMM: V = Z~ - 2*step*( (Z@M) - YAt ) ----------------
// split-bf16: acc = Zh*Mh + Zh*Ml + Zl*Mh (fp32 accumulate), Z~ = Zh + Zl.
// 64x64 tile, 4 waves of 32x32, XOR-swizzled LDS staged via global_load_lds.
__global__ __launch_bounds__(256, 1) void fista_gemm(
    const unsigned short* __restrict__ Zh, const unsigned short* __restrict__ Zl,
    const unsigned short* __restrict__ Mh, const unsigned short* __restrict__ Ml,
    const float* __restrict__ YAt, const float* __restrict__ stepPtr,
    float* __restrict__ V) {
  __shared__ __align__(16) unsigned short sAh[64 * 64], sAl[64 * 64];
  __shared__ __align__(16) unsigned short sBh[64 * 64], sBl[64 * 64];
  const int tid = threadIdx.x;
  const int rowBase = blockIdx.y * 64;
  const int colBase = blockIdx.x * 64;
  const int l = tid & 63;
  const int wid = tid >> 6;
  const int wr = (wid >> 1) * 32;  // wave row offset in tile
  const int wc = (wid & 1) * 32;   // wave col offset in tile
  const int q = l >> 4, m = l & 15;

  floatx4 acc[2][2];
#pragma unroll
  for (int t = 0; t < 2; ++t)
#pragma unroll
    for (int u = 0; u < 2; ++u) acc[t][u] = (floatx4){0.f, 0.f, 0.f, 0.f};

  // staging geometry: buffer = 64 rows x 8 chunks(16B); lane-contiguous LDS,
  // XOR swizzle (chunk ^ row%8) applied on the GLOBAL side.
  const int idx0 = tid, idx1 = 256 + tid;
  const int r0 = idx0 >> 3, c0 = ((idx0 & 7) ^ (r0 & 7)) * 8;
  const int r1 = idx1 >> 3, c1 = ((idx1 & 7) ^ (r1 & 7)) * 8;
  const size_t ga0 = (size_t)(rowBase + r0) * N + c0;
  const size_t ga1 = (size_t)(rowBase + r1) * N + c1;
  const size_t gb0 = (size_t)(colBase + r0) * N + c0;
  const size_t gb1 = (size_t)(colBase + r1) * N + c1;

  for (int k0 = 0; k0 < N; k0 += 64) {
    __syncthreads();
    GLD16(Zh + ga0 + k0, &sAh[idx0 * 8]);
    GLD16(Zh + ga1 + k0, &sAh[idx1 * 8]);
    GLD16(Zl + ga0 + k0, &sAl[idx0 * 8]);
    GLD16(Zl + ga1 + k0, &sAl[idx1 * 8]);
    GLD16(Mh + gb0 + k0, &sBh[idx0 * 8]);
    GLD16(Mh + gb1 + k0, &sBh[idx1 * 8]);
    GLD16(Ml + gb0 + k0, &sBl[idx0 * 8]);
    GLD16(Ml + gb1 + k0, &sBl[idx1 * 8]);
    __syncthreads();
#pragma unroll
    for (int s = 0; s < 2; ++s) {
      short8 ah[2], al[2], bh[2], bl[2];
#pragma unroll
      for (int t = 0; t < 2; ++t) {
        int ar = wr + t * 16 + m;
        int sa = ((s * 4 + q) ^ (ar & 7)) * 8;
        ah[t] = *(const short8*)&sAh[ar * 64 + sa];
        al[t] = *(const short8*)&sAl[ar * 64 + sa];
        int br = wc + t * 16 + m;
        int sb = ((s * 4 + q) ^ (br & 7)) * 8;
        bh[t] = *(const short8*)&sBh[br * 64 + sb];
        bl[t] = *(const short8*)&sBl[br * 64 + sb];
      }
#pragma unroll
      for (int t = 0; t < 2; ++t)
#pragma unroll
        for (int u = 0; u < 2; ++u) {
          acc[t][u] = __builtin_amdgcn_mfma_f32_16x16x32_bf16(ah[t], bh[u], acc[t][u], 0, 0, 0);
          acc[t][u] = __builtin_amdgcn_mfma_f32_16x16x32_bf16(ah[t], bl[u], acc[t][u], 0, 0, 0);
          acc[t][u] = __builtin_amdgcn_mfma_f32_16x16x32_bf16(al[t], bh[u], acc[t][u], 0, 0, 0);
        }
    }
  }

  // epilogue: C/D layout col = lane&15, row = (lane>>4)*4 + reg
  const float c2 = 2.0f * stepPtr[0];
#pragma unroll
  for (int t = 0; t < 2; ++t) {
    int rowb = rowBase + wr + t * 16 + q * 4;
#pragma unroll
    for (int u = 0; u < 2; ++u) {
      int col = colBase + wc + u * 16 + m;
#pragma unroll
      for (int r = 0; r < 4; ++r) {
        size_t off = (size_t)(rowb + r) * N + col;
        float z = bf2f(Zh[off]) + bf2f(Zl[off]);
        V[off] = z - c2 * (acc[t][u][r] - YAt[off]);
      }
    }
  }
}

// ---------------- matvec: w = scale * (M v) ----------------
__global__ __launch_bounds__(256) void matvec_k(
    const float* __restrict__ Mm, const float* __restrict__ v,
    float* __restrict__ w, float scale) {
  int tid = threadIdx.x;
  int lane = tid & 63, wid = tid >> 6;
  int row = blockIdx.x * 4 + wid;
  const float* mr = Mm + (size_t)row * N;
  float s = 0.0f;
#pragma unroll
  for (int j = 0; j < N; j += 64) s = fmaf(mr[j + lane], v[j + lane], s);
  s = wave_reduce(s);
  if (lane == 0) w[row] = s * scale;
}

// ---------------- Rayleigh -> step ----------------
__global__ __launch_bounds__(256) void rayleigh_k(
    const float* __restrict__ u, const float* __restrict__ w,
    float* __restrict__ stepOut) {
  int tid = threadIdx.x;
  float r1 = 0.0f, r2 = 0.0f;
  for (int j = tid; j < N; j += 256) {
    float uu = u[j];
    r1 = fmaf(uu, w[j], r1);
    r2 = fmaf(uu, uu, r2);
  }
  r1 = wave_reduce(r1);
  r2 = wave_reduce(r2);
  __shared__ float sh[8];
  int lane = tid & 63, wid = tid >> 6;
  if (lane == 0) { sh[wid] = r1; sh[4 + wid] = r2; }
  __syncthreads();
  if (tid == 0) {
    float R1 = sh[0] + sh[1] + sh[2] + sh[3];
    float R2 = sh[4] + sh[5] + sh[6] + sh[7];
    float L = 2.0f * (R1 / R2);
    stepOut[0] = 1.0f / (L + 1e-8f);
  }
}

// ---------------- init ----------------
__global__ __launch_bounds__(256) void init_k(float* __restrict__ X,
                                              unsigned short* __restrict__ Zh,
                                              unsigned short* __restrict__ Zl,
                                              float* __restrict__ v) {
  int i = blockIdx.x * 256 + threadIdx.x;
  const float c = 1.0f / (float)N;
  X[i] = c;
  Zh[i] = f2bf(c);  // 2^-10 exact in bf16
  Zl[i] = 0;
  if (i < N) v[i] = c;
}

// ---------------- simplex projection (Michelot) + FISTA update ----------------
__global__ __launch_bounds__(256) void fista_update_k(
    const float* __restrict__ V, float* __restrict__ X,
    unsigned short* __restrict__ Zh, unsigned short* __restrict__ Zl,
    float mom) {
  __shared__ float sh[8];
  const int r = blockIdx.x, tid = threadIdx.x;
  const int lane = tid & 63, wid = tid >> 6;
  float4 v4 = ((const float4*)(V + (size_t)r * N))[tid];
  float vl[4] = {v4.x, v4.y, v4.z, v4.w};
  float s = vl[0] + vl[1] + vl[2] + vl[3];
  s = wave_reduce(s);
  if (lane == 0) sh[wid] = s;
  __syncthreads();
  float theta = (sh[0] + sh[1] + sh[2] + sh[3] - 1.0f) * (1.0f / (float)N);
  for (int it = 0; it < 40; ++it) {
    float sa = 0.0f, ka = 0.0f;
#pragma unroll
    for (int j = 0; j < 4; ++j)
      if (vl[j] > theta) { sa += vl[j]; ka += 1.0f; }
    sa = wave_reduce(sa);
    ka = wave_reduce(ka);
    __syncthreads();
    if (lane == 0) { sh[wid] = sa; sh[4 + wid] = ka; }
    __syncthreads();
    float SA = sh[0] + sh[1] + sh[2] + sh[3];
    float KA = fmaxf(sh[4] + sh[5] + sh[6] + sh[7], 1.0f);
    float tn = (SA - 1.0f) / KA;
    bool done = (tn - theta) <= (1e-7f * fabsf(tn) + 1e-12f);  // block-uniform
    theta = tn;
    if (done) break;
  }
  float4 x4 = ((const float4*)(X + (size_t)r * N))[tid];
  float xo[4] = {x4.x, x4.y, x4.z, x4.w};
  float xn[4], zn[4];
#pragma unroll
  for (int j = 0; j < 4; ++j) {
    xn[j] = fmaxf(vl[j] - theta, 0.0f);
    zn[j] = xn[j] + mom * (xn[j] - xo[j]);
  }
  ((float4*)(X + (size_t)r * N))[tid] = make_float4(xn[0], xn[1], xn[2], xn[3]);
  ushort4 zh, zl;
  zh.x = f2bf(zn[0]); zl.x = f2bf(zn[0] - bf2f(zh.x));
  zh.y = f2bf(zn[1]); zl.y = f2bf(zn[1] - bf2f(zh.y));
  zh.z = f2bf(zn[2]); zl.z = f2bf(zn[2] - bf2f(zh.z));
  zh.w = f2bf(zn[3]); zl.w = f2bf(zn[3] - bf2f(zh.w));
  ((ushort4*)(Zh + (size_t)r * N))[tid] = zh;
  ((ushort4*)(Zl + (size_t)r * N))[tid] = zl;
}

// ---------------- transpose An [N x D] -> AnT [D x N] ----------------
__global__ void transpose_k(const float* __restrict__ An, float* __restrict__ AnT) {
  __shared__ float t[32][33];
  int x = blockIdx.x * 32 + threadIdx.x;
  int y0 = blockIdx.y * 32;
#pragma unroll
  for (int j = 0; j < 32; j += 8)
    t[threadIdx.y + j][threadIdx.x] = An[(size_t)(y0 + threadIdx.y + j) * D + x];
  __syncthreads();
  int xo = y0 + threadIdx.x;
  int yo0 = blockIdx.x * 32;
#pragma unroll
  for (int j = 0; j < 32; j += 8)
    AnT[(size_t)(yo0 + threadIdx.y + j) * N + xo] = t[threadIdx.x][threadIdx.y + j];
}

// ---------------- per-row cosine ----------------
__global__ __launch_bounds__(128) void cos_k(const float* __restrict__ P,
                                             const float* __restrict__ Yn,
                                             float* __restrict__ cb) {
  int r = blockIdx.x, tid = threadIdx.x;
  float4 p = ((const float4*)(P + (size_t)r * D))[tid];
  float4 y = ((const float4*)(Yn + (size_t)r * D))[tid];
  float d  = p.x * y.x + p.y * y.y + p.z * y.z + p.w * y.w;
  float np = p.x * p.x + p.y * p.y + p.z * p.z + p.w * p.w;
  float ny = y.x * y.x + y.y * y.y + y.z * y.z + y.w * y.w;
  d = wave_reduce(d);
  np = wave_reduce(np);
  ny = wave_reduce(ny);
  __shared__ float sh[6];
  int lane = tid & 63, wid = tid >> 6;
  if (lane == 0) { sh[wid] = d; sh[2 + wid] = np; sh[4 + wid] = ny; }
  __syncthreads();
  if (tid == 0) {
    float dt = sh[0] + sh[1], npt = sh[2] + sh[3], nyt = sh[4] + sh[5];
    cb[r] = dt / (fmaxf(sqrtf(npt), 1e-8f) * fmaxf(sqrtf(nyt), 1e-8f));
  }
}

// ---------------- mean ----------------
__global__ __launch_bounds__(256) void mean_k(const float* __restrict__ cb,
                                              float* __restrict__ out) {
  int tid = threadIdx.x;
  float s = cb[tid] + cb[tid + 256] + cb[tid + 512] + cb[tid + 768];
  s = wave_reduce(s);
  __shared__ float sh[4];
  int lane = tid & 63, wid = tid >> 6;
  if (lane == 0) sh[wid] = s;
  __syncthreads();
  if (tid == 0) out[0] = (sh[0] + sh[1] + sh[2] + sh[3]) * (1.0f / (float)N);
}

// ---------------- host orchestration ----------------
extern "C" void kernel_launch(void* const* d_in, const int* in_sizes, int n_in,
                              void* d_out, int out_size, void* d_ws, size_t ws_size,
                              hipStream_t stream) {
  const float* fea1 = (const float*)d_in[0];
  const float* fea2 = (const float*)d_in[1];
  float* ws = (float*)d_ws;
  float* Yn  = ws;                              // N*D
  float* An  = Yn + (size_t)N * D;              // N*D
  float* Mm  = An + (size_t)N * D;              // N*N
  float* YAt = Mm + (size_t)N * N;              // N*N
  float* X   = YAt + (size_t)N * N;             // N*N
  float* V   = X + (size_t)N * N;               // N*N
  unsigned short* Zh = (unsigned short*)(V + (size_t)N * N);  // N*N bf16
  unsigned short* Zl = Zh + (size_t)N * N;
  unsigned short* Mh = Zl + (size_t)N * N;
  unsigned short* Ml = Mh + (size_t)N * N;
  float* vp   = (float*)(Ml + (size_t)N * N);
  float* wp   = vp + N;
  float* stepP = wp + N;
  // dead-buffer reuse after the FISTA loop:
  float* AnT = V;
  float* P   = V + (size_t)N * D;
  float* cosb = Mm;

  normalize_k<<<2 * N, 256, 0, stream>>>(fea1, fea2, Yn, An);
  gemm_nt<<<dim3(N / 64, N / 64), 256, 0, stream>>>(An, D, An, D, Mm, N, D);
  gemm_nt<<<dim3(N / 64, N / 64), 256, 0, stream>>>(Yn, D, An, D, YAt, N, D);
  split_k<<<(N * N) / 256, 256, 0, stream>>>(Mm, Mh, Ml);
  init_k<<<(N * N) / 256, 256, 0, stream>>>(X, Zh, Zl, vp);

  float* pv = vp;
  float* pw = wp;
  for (int i = 0; i < PIT; ++i) {
    matvec_k<<<N / 4, 256, 0, stream>>>(Mm, pv, pw, 0.125f);
    float* t = pv; pv = pw; pw = t;
  }
  matvec_k<<<N / 4, 256, 0, stream>>>(Mm, pv, pw, 1.0f);
  rayleigh_k<<<1, 256, 0, stream>>>(pv, pw, stepP);

  float t = 1.0f;
  for (int it = 0; it < NIT; ++it) {
    fista_gemm<<<dim3(N / 64, N / 64), 256, 0, stream>>>(Zh, Zl, Mh, Ml, YAt,
                                                         stepP, V);
    float tn = 0.5f * (1.0f + sqrtf(1.0f + 4.0f * t * t));
    float mom = (t - 1.0f) / tn;
    t = tn;
    fista_update_k<<<N, 256, 0, stream>>>(V, X, Zh, Zl, mom);
  }

  transpose_k<<<dim3(D / 32, N / 32), dim3(32, 8), 0, stream>>>(An, AnT);
  gemm_nt<<<dim3(D / 64, N / 64), 256, 0, stream>>>(X, N, AnT, N, P, D, N);
  cos_k<<<N, 128, 0, stream>>>(P, Yn, cosb);
  mean_k<<<1, 256, 0, stream>>>(cosb, (float*)d_out);
}

// Round 3
// 4894.500 us; speedup vs baseline: 2.5915x; 1.2226x over previous
//
#include <hip/hip_runtime.h>
#include <math.h>

#define N 1024
#define D 512
#define NIT 200
#define PIT 50

typedef __attribute__((ext_vector_type(8))) short short8;
typedef __attribute__((ext_vector_type(4))) float floatx4;

// ---------------- helpers ----------------
__device__ __forceinline__ float wave_reduce(float v) {
#pragma unroll
  for (int off = 32; off; off >>= 1) v += __shfl_xor(v, off, 64);
  return v;
}

__device__ __forceinline__ unsigned short f2bf(float x) {
  unsigned int u = __float_as_uint(x);
  u += 0x7FFF + ((u >> 16) & 1);  // round-to-nearest-even
  return (unsigned short)(u >> 16);
}
__device__ __forceinline__ float bf2f(unsigned short h) {
  return __uint_as_float(((unsigned int)h) << 16);
}

// async global->LDS, 16 B per lane; LDS dest must be lane-contiguous
#define GLD16(g, l)                                                     \
  __builtin_amdgcn_global_load_lds(                                     \
      (__attribute__((address_space(1))) void*)(g),                     \
      (__attribute__((address_space(3))) void*)(l), 16, 0, 0)

// ---------------- row normalize ----------------
__global__ __launch_bounds__(256) void normalize_k(
    const float* __restrict__ f1, const float* __restrict__ f2,
    float* __restrict__ Yn, float* __restrict__ An) {
  int b = blockIdx.x;
  const float* src;
  float* dst;
  if (b < N) { src = f1 + (size_t)b * D; dst = Yn + (size_t)b * D; }
  else       { src = f2 + (size_t)(b - N) * D; dst = An + (size_t)(b - N) * D; }
  int tid = threadIdx.x;
  float2 e = ((const float2*)src)[tid];
  float ss = e.x * e.x + e.y * e.y;
  ss = wave_reduce(ss);
  __shared__ float sh[4];
  int lane = tid & 63, wid = tid >> 6;
  if (lane == 0) sh[wid] = ss;
  __syncthreads();
  float total = sh[0] + sh[1] + sh[2] + sh[3];
  float rn = 1.0f / sqrtf(total);
  ((float2*)dst)[tid] = make_float2(e.x * rn, e.y * rn);
}

// ---------------- fp32 NT GEMM (one-time uses: M, YAt, final P) ----------------
#define LDT 68
__global__ __launch_bounds__(256) void gemm_nt(
    const float* __restrict__ A, int lda,
    const float* __restrict__ B, int ldb,
    float* __restrict__ C, int ldc, int K) {
  __shared__ __align__(16) float At[32][LDT];
  __shared__ __align__(16) float Bt[32][LDT];
  const int tid = threadIdx.x;
  const int rowBase = blockIdx.y * 64;
  const int colBase = blockIdx.x * 64;
  const int tx = tid & 15, ty = tid >> 4;
  float acc[4][4] = {};
  const int r0 = tid >> 3;
  const int r1 = r0 + 32;
  const int kc = (tid & 7) * 4;

  for (int k0 = 0; k0 < K; k0 += 32) {
    __syncthreads();
    {
      float4 av = *(const float4*)(A + (size_t)(rowBase + r0) * lda + k0 + kc);
      At[kc + 0][r0] = av.x; At[kc + 1][r0] = av.y; At[kc + 2][r0] = av.z; At[kc + 3][r0] = av.w;
      float4 bv = *(const float4*)(B + (size_t)(colBase + r0) * ldb + k0 + kc);
      Bt[kc + 0][r0] = bv.x; Bt[kc + 1][r0] = bv.y; Bt[kc + 2][r0] = bv.z; Bt[kc + 3][r0] = bv.w;
      av = *(const float4*)(A + (size_t)(rowBase + r1) * lda + k0 + kc);
      At[kc + 0][r1] = av.x; At[kc + 1][r1] = av.y; At[kc + 2][r1] = av.z; At[kc + 3][r1] = av.w;
      bv = *(const float4*)(B + (size_t)(colBase + r1) * ldb + k0 + kc);
      Bt[kc + 0][r1] = bv.x; Bt[kc + 1][r1] = bv.y; Bt[kc + 2][r1] = bv.z; Bt[kc + 3][r1] = bv.w;
    }
    __syncthreads();
#pragma unroll
    for (int kk = 0; kk < 32; ++kk) {
      float4 a4 = *(const float4*)&At[kk][ty * 4];
      float4 b4 = *(const float4*)&Bt[kk][tx * 4];
      float a[4] = {a4.x, a4.y, a4.z, a4.w};
      float b[4] = {b4.x, b4.y, b4.z, b4.w};
#pragma unroll
      for (int r = 0; r < 4; ++r)
#pragma unroll
        for (int c = 0; c < 4; ++c) acc[r][c] = fmaf(a[r], b[c], acc[r][c]);
    }
  }
#pragma unroll
  for (int r = 0; r < 4; ++r) {
    int i = rowBase + ty * 4 + r;
    size_t off = (size_t)i * ldc + colBase + tx * 4;
    *(float4*)(C + off) = make_float4(acc[r][0], acc[r][1], acc[r][2], acc[r][3]);
  }
}

// ---------------- split fp32 -> bf16 hi/lo ----------------
__global__ __launch_bounds__(256) void split_k(const float* __restrict__ Mm,
                                               unsigned short* __restrict__ Mh,
                                               unsigned short* __restrict__ Ml) {
  int i = blockIdx.x * 256 + threadIdx.x;
  float x = Mm[i];
  unsigned short h = f2bf(x);
  Mh[i] = h;
  Ml[i] = f2bf(x - bf2f(h));
}

// ---------------- FISTA GEMM (K-split + LDS double buffer) ----------------
// Computes raw partial acc of Z@M over K-half blockIdx.z into Vp[z].
// split-bf16: acc = Zh*Mh + Zh*Ml + Zl*Mh (fp32 accumulate).
#define KTILES 8  // 512 / 64
__global__ __launch_bounds__(256, 2) void fista_gemm(
    const unsigned short* __restrict__ Zh, const unsigned short* __restrict__ Zl,
    const unsigned short* __restrict__ Mh, const unsigned short* __restrict__ Ml,
    float* __restrict__ Vp) {
  __shared__ __align__(16) unsigned short sAh[2][64 * 64], sAl[2][64 * 64];
  __shared__ __align__(16) unsigned short sBh[2][64 * 64], sBl[2][64 * 64];
  const int tid = threadIdx.x;
  const int rowBase = blockIdx.y * 64;
  const int colBase = blockIdx.x * 64;
  const int kbase = blockIdx.z * (KTILES * 64);
  const int l = tid & 63;
  const int wid = tid >> 6;
  const int wr = (wid >> 1) * 32;
  const int wc = (wid & 1) * 32;
  const int q = l >> 4, m = l & 15;

  floatx4 acc[2][2];
#pragma unroll
  for (int t = 0; t < 2; ++t)
#pragma unroll
    for (int u = 0; u < 2; ++u) acc[t][u] = (floatx4){0.f, 0.f, 0.f, 0.f};

  // staging geometry: 64 rows x 8 chunks(16B); lane-contiguous LDS,
  // XOR swizzle (chunk ^ row%8) applied on the GLOBAL side.
  const int idx0 = tid, idx1 = 256 + tid;
  const int r0 = idx0 >> 3, c0 = ((idx0 & 7) ^ (r0 & 7)) * 8;
  const int r1 = idx1 >> 3, c1 = ((idx1 & 7) ^ (r1 & 7)) * 8;
  const size_t ga0 = (size_t)(rowBase + r0) * N + c0 + kbase;
  const size_t ga1 = (size_t)(rowBase + r1) * N + c1 + kbase;
  const size_t gb0 = (size_t)(colBase + r0) * N + c0 + kbase;
  const size_t gb1 = (size_t)(colBase + r1) * N + c1 + kbase;

#define ISSUE(buf, koff)                                   \
  do {                                                     \
    GLD16(Zh + ga0 + (koff), &sAh[buf][idx0 * 8]);         \
    GLD16(Zh + ga1 + (koff), &sAh[buf][idx1 * 8]);         \
    GLD16(Zl + ga0 + (koff), &sAl[buf][idx0 * 8]);         \
    GLD16(Zl + ga1 + (koff), &sAl[buf][idx1 * 8]);         \
    GLD16(Mh + gb0 + (koff), &sBh[buf][idx0 * 8]);         \
    GLD16(Mh + gb1 + (koff), &sBh[buf][idx1 * 8]);         \
    GLD16(Ml + gb0 + (koff), &sBl[buf][idx0 * 8]);         \
    GLD16(Ml + gb1 + (koff), &sBl[buf][idx1 * 8]);         \
  } while (0)

  ISSUE(0, 0);
  __syncthreads();  // drains vmcnt -> buf 0 ready

  for (int kt = 0; kt < KTILES; ++kt) {
    const int cur = kt & 1;
    if (kt + 1 < KTILES) ISSUE(cur ^ 1, (kt + 1) * 64);  // prefetch next tile
#pragma unroll
    for (int s = 0; s < 2; ++s) {
      short8 ah[2], al[2], bh[2], bl[2];
#pragma unroll
      for (int t = 0; t < 2; ++t) {
        int ar = wr + t * 16 + m;
        int sa = ((s * 4 + q) ^ (ar & 7)) * 8;
        ah[t] = *(const short8*)&sAh[cur][ar * 64 + sa];
        al[t] = *(const short8*)&sAl[cur][ar * 64 + sa];
        int br = wc + t * 16 + m;
        int sb = ((s * 4 + q) ^ (br & 7)) * 8;
        bh[t] = *(const short8*)&sBh[cur][br * 64 + sb];
        bl[t] = *(const short8*)&sBl[cur][br * 64 + sb];
      }
#pragma unroll
      for (int t = 0; t < 2; ++t)
#pragma unroll
        for (int u = 0; u < 2; ++u) {
          acc[t][u] = __builtin_amdgcn_mfma_f32_16x16x32_bf16(ah[t], bh[u], acc[t][u], 0, 0, 0);
          acc[t][u] = __builtin_amdgcn_mfma_f32_16x16x32_bf16(ah[t], bl[u], acc[t][u], 0, 0, 0);
          acc[t][u] = __builtin_amdgcn_mfma_f32_16x16x32_bf16(al[t], bh[u], acc[t][u], 0, 0, 0);
        }
    }
    __syncthreads();  // prefetched loads have had the compute phase to land
  }
#undef ISSUE

  // epilogue: raw partial sums; C/D layout col = lane&15, row = (lane>>4)*4 + reg
  float* out = Vp + (size_t)blockIdx.z * N * N;
#pragma unroll
  for (int t = 0; t < 2; ++t) {
    int rowb = rowBase + wr + t * 16 + q * 4;
#pragma unroll
    for (int u = 0; u < 2; ++u) {
      int col = colBase + wc + u * 16 + m;
#pragma unroll
      for (int r = 0; r < 4; ++r)
        out[(size_t)(rowb + r) * N + col] = acc[t][u][r];
    }
  }
}

// ---------------- matvec: w = scale * (M v) ----------------
__global__ __launch_bounds__(256) void matvec_k(
    const float* __restrict__ Mm, const float* __restrict__ v,
    float* __restrict__ w, float scale) {
  int tid = threadIdx.x;
  int lane = tid & 63, wid = tid >> 6;
  int row = blockIdx.x * 4 + wid;
  const float* mr = Mm + (size_t)row * N;
  float s = 0.0f;
#pragma unroll
  for (int j = 0; j < N; j += 64) s = fmaf(mr[j + lane], v[j + lane], s);
  s = wave_reduce(s);
  if (lane == 0) w[row] = s * scale;
}

// ---------------- Rayleigh -> step ----------------
__global__ __launch_bounds__(256) void rayleigh_k(
    const float* __restrict__ u, const float* __restrict__ w,
    float* __restrict__ stepOut) {
  int tid = threadIdx.x;
  float r1 = 0.0f, r2 = 0.0f;
  for (int j = tid; j < N; j += 256) {
    float uu = u[j];
    r1 = fmaf(uu, w[j], r1);
    r2 = fmaf(uu, uu, r2);
  }
  r1 = wave_reduce(r1);
  r2 = wave_reduce(r2);
  __shared__ float sh[8];
  int lane = tid & 63, wid = tid >> 6;
  if (lane == 0) { sh[wid] = r1; sh[4 + wid] = r2; }
  __syncthreads();
  if (tid == 0) {
    float R1 = sh[0] + sh[1] + sh[2] + sh[3];
    float R2 = sh[4] + sh[5] + sh[6] + sh[7];
    float L = 2.0f * (R1 / R2);
    stepOut[0] = 1.0f / (L + 1e-8f);
  }
}

// ---------------- init ----------------
__global__ __launch_bounds__(256) void init_k(float* __restrict__ X,
                                              unsigned short* __restrict__ Zh,
                                              unsigned short* __restrict__ Zl,
                                              float* __restrict__ v) {
  int i = blockIdx.x * 256 + threadIdx.x;
  const float c = 1.0f / (float)N;
  X[i] = c;
  Zh[i] = f2bf(c);  // 2^-10 exact in bf16
  Zl[i] = 0;
  if (i < N) v[i] = c;
}

// ---------------- combine + simplex projection (Michelot) + FISTA update ------
__global__ __launch_bounds__(256) void fista_update_k(
    const float* __restrict__ Vp0, const float* __restrict__ Vp1,
    const float* __restrict__ YAt, const float* __restrict__ stepPtr,
    float* __restrict__ X,
    unsigned short* __restrict__ Zh, unsigned short* __restrict__ Zl,
    float mom) {
  __shared__ float sh[8];
  const int r = blockIdx.x, tid = threadIdx.x;
  const int lane = tid & 63, wid = tid >> 6;
  const float c2 = 2.0f * stepPtr[0];
  float4 a0 = ((const float4*)(Vp0 + (size_t)r * N))[tid];
  float4 a1 = ((const float4*)(Vp1 + (size_t)r * N))[tid];
  float4 ya = ((const float4*)(YAt + (size_t)r * N))[tid];
  ushort4 zh4 = ((const ushort4*)(Zh + (size_t)r * N))[tid];
  ushort4 zl4 = ((const ushort4*)(Zl + (size_t)r * N))[tid];
  float vl[4];
  vl[0] = bf2f(zh4.x) + bf2f(zl4.x) - c2 * (a0.x + a1.x - ya.x);
  vl[1] = bf2f(zh4.y) + bf2f(zl4.y) - c2 * (a0.y + a1.y - ya.y);
  vl[2] = bf2f(zh4.z) + bf2f(zl4.z) - c2 * (a0.z + a1.z - ya.z);
  vl[3] = bf2f(zh4.w) + bf2f(zl4.w) - c2 * (a0.w + a1.w - ya.w);

  float s = vl[0] + vl[1] + vl[2] + vl[3];
  s = wave_reduce(s);
  if (lane == 0) sh[wid] = s;
  __syncthreads();
  float theta = (sh[0] + sh[1] + sh[2] + sh[3] - 1.0f) * (1.0f / (float)N);
  for (int it = 0; it < 40; ++it) {
    float sa = 0.0f, ka = 0.0f;
#pragma unroll
    for (int j = 0; j < 4; ++j)
      if (vl[j] > theta) { sa += vl[j]; ka += 1.0f; }
    sa = wave_reduce(sa);
    ka = wave_reduce(ka);
    __syncthreads();
    if (lane == 0) { sh[wid] = sa; sh[4 + wid] = ka; }
    __syncthreads();
    float SA = sh[0] + sh[1] + sh[2] + sh[3];
    float KA = fmaxf(sh[4] + sh[5] + sh[6] + sh[7], 1.0f);
    float tn = (SA - 1.0f) / KA;
    bool done = (tn - theta) <= (1e-7f * fabsf(tn) + 1e-12f);  // block-uniform
    theta = tn;
    if (done) break;
  }
  float4 x4 = ((const float4*)(X + (size_t)r * N))[tid];
  float xo[4] = {x4.x, x4.y, x4.z, x4.w};
  float xn[4], zn[4];
#pragma unroll
  for (int j = 0; j < 4; ++j) {
    xn[j] = fmaxf(vl[j] - theta, 0.0f);
    zn[j] = xn[j] + mom * (xn[j] - xo[j]);
  }
  ((float4*)(X + (size_t)r * N))[tid] = make_float4(xn[0], xn[1], xn[2], xn[3]);
  ushort4 zh, zl;
  zh.x = f2bf(zn[0]); zl.x = f2bf(zn[0] - bf2f(zh.x));
  zh.y = f2bf(zn[1]); zl.y = f2bf(zn[1] - bf2f(zh.y));
  zh.z = f2bf(zn[2]); zl.z = f2bf(zn[2] - bf2f(zh.z));
  zh.w = f2bf(zn[3]); zl.w = f2bf(zn[3] - bf2f(zh.w));
  ((ushort4*)(Zh + (size_t)r * N))[tid] = zh;
  ((ushort4*)(Zl + (size_t)r * N))[tid] = zl;
}

// ---------------- transpose An [N x D] -> AnT [D x N] ----------------
__global__ void transpose_k(const float* __restrict__ An, float* __restrict__ AnT) {
  __shared__ float t[32][33];
  int x = blockIdx.x * 32 + threadIdx.x;
  int y0 = blockIdx.y * 32;
#pragma unroll
  for (int j = 0; j < 32; j += 8)
    t[threadIdx.y + j][threadIdx.x] = An[(size_t)(y0 + threadIdx.y + j) * D + x];
  __syncthreads();
  int xo = y0 + threadIdx.x;
  int yo0 = blockIdx.x * 32;
#pragma unroll
  for (int j = 0; j < 32; j += 8)
    AnT[(size_t)(yo0 + threadIdx.y + j) * N + xo] = t[threadIdx.x][threadIdx.y + j];
}

// ---------------- per-row cosine ----------------
__global__ __launch_bounds__(128) void cos_k(const float* __restrict__ P,
                                             const float* __restrict__ Yn,
                                             float* __restrict__ cb) {
  int r = blockIdx.x, tid = threadIdx.x;
  float4 p = ((const float4*)(P + (size_t)r * D))[tid];
  float4 y = ((const float4*)(Yn + (size_t)r * D))[tid];
  float d  = p.x * y.x + p.y * y.y + p.z * y.z + p.w * y.w;
  float np = p.x * p.x + p.y * p.y + p.z * p.z + p.w * p.w;
  float ny = y.x * y.x + y.y * y.y + y.z * y.z + y.w * y.w;
  d = wave_reduce(d);
  np = wave_reduce(np);
  ny = wave_reduce(ny);
  __shared__ float sh[6];
  int lane = tid & 63, wid = tid >> 6;
  if (lane == 0) { sh[wid] = d; sh[2 + wid] = np; sh[4 + wid] = ny; }
  __syncthreads();
  if (tid == 0) {
    float dt = sh[0] + sh[1], npt = sh[2] + sh[3], nyt = sh[4] + sh[5];
    cb[r] = dt / (fmaxf(sqrtf(npt), 1e-8f) * fmaxf(sqrtf(nyt), 1e-8f));
  }
}

// ---------------- mean ----------------
__global__ __launch_bounds__(256) void mean_k(const float* __restrict__ cb,
                                              float* __restrict__ out) {
  int tid = threadIdx.x;
  float s = cb[tid] + cb[tid + 256] + cb[tid + 512] + cb[tid + 768];
  s = wave_reduce(s);
  __shared__ float sh[4];
  int lane = tid & 63, wid = tid >> 6;
  if (lane == 0) sh[wid] = s;
  __syncthreads();
  if (tid == 0) out[0] = (sh[0] + sh[1] + sh[2] + sh[3]) * (1.0f / (float)N);
}

// ---------------- host orchestration ----------------
extern "C" void kernel_launch(void* const* d_in, const int* in_sizes, int n_in,
                              void* d_out, int out_size, void* d_ws, size_t ws_size,
                              hipStream_t stream) {
  const float* fea1 = (const float*)d_in[0];
  const float* fea2 = (const float*)d_in[1];
  float* ws = (float*)d_ws;
  float* Yn  = ws;                              // N*D
  float* An  = Yn + (size_t)N * D;              // N*D
  float* Mm  = An + (size_t)N * D;              // N*N
  float* YAt = Mm + (size_t)N * N;              // N*N
  float* X   = YAt + (size_t)N * N;             // N*N
  float* Vp0 = X + (size_t)N * N;               // N*N
  float* Vp1 = Vp0 + (size_t)N * N;             // N*N
  unsigned short* Zh = (unsigned short*)(Vp1 + (size_t)N * N);  // N*N bf16
  unsigned short* Zl = Zh + (size_t)N * N;
  unsigned short* Mh = Zl + (size_t)N * N;
  unsigned short* Ml = Mh + (size_t)N * N;
  float* vp   = (float*)(Ml + (size_t)N * N);
  float* wp   = vp + N;
  float* stepP = wp + N;
  // dead-buffer reuse after the FISTA loop:
  float* AnT = Vp0;                     // D*N
  float* P   = Vp0 + (size_t)N * D;     // N*D
  float* cosb = Mm;

  normalize_k<<<2 * N, 256, 0, stream>>>(fea1, fea2, Yn, An);
  gemm_nt<<<dim3(N / 64, N / 64), 256, 0, stream>>>(An, D, An, D, Mm, N, D);
  gemm_nt<<<dim3(N / 64, N / 64), 256, 0, stream>>>(Yn, D, An, D, YAt, N, D);
  split_k<<<(N * N) / 256, 256, 0, stream>>>(Mm, Mh, Ml);
  init_k<<<(N * N) / 256, 256, 0, stream>>>(X, Zh, Zl, vp);

  float* pv = vp;
  float* pw = wp;
  for (int i = 0; i < PIT; ++i) {
    matvec_k<<<N / 4, 256, 0, stream>>>(Mm, pv, pw, 0.125f);
    float* t = pv; pv = pw; pw = t;
  }
  matvec_k<<<N / 4, 256, 0, stream>>>(Mm, pv, pw, 1.0f);
  rayleigh_k<<<1, 256, 0, stream>>>(pv, pw, stepP);

  float t = 1.0f;
  for (int it = 0; it < NIT; ++it) {
    fista_gemm<<<dim3(N / 64, N / 64, 2), 256, 0, stream>>>(Zh, Zl, Mh, Ml, Vp0);
    float tn = 0.5f * (1.0f + sqrtf(1.0f + 4.0f * t * t));
    float mom = (t - 1.0f) / tn;
    t = tn;
    fista_update_k<<<N, 256, 0, stream>>>(Vp0, Vp1, YAt, stepP, X, Zh, Zl, mom);
  }

  transpose_k<<<dim3(D / 32, N / 32), dim3(32, 8), 0, stream>>>(An, AnT);
  gemm_nt<<<dim3(D / 64, N / 64), 256, 0, stream>>>(X, N, AnT, N, P, D, N);
  cos_k<<<N, 128, 0, stream>>>(P, Yn, cosb);
  mean_k<<<1, 256, 0, stream>>>(cosb, (float*)d_out);
}

// Round 4
// 4735.617 us; speedup vs baseline: 2.6785x; 1.0336x over previous
//
#include <hip/hip_runtime.h>
#include <math.h>

#define N 1024
#define D 512
#define NIT 200
#define PIT 50

typedef __attribute__((ext_vector_type(8))) short short8;
typedef __attribute__((ext_vector_type(4))) float floatx4;

// ---------------- helpers ----------------
__device__ __forceinline__ float wave_reduce(float v) {
#pragma unroll
  for (int off = 32; off; off >>= 1) v += __shfl_xor(v, off, 64);
  return v;
}

__device__ __forceinline__ unsigned short f2bf(float x) {
  unsigned int u = __float_as_uint(x);
  u += 0x7FFF + ((u >> 16) & 1);  // round-to-nearest-even
  return (unsigned short)(u >> 16);
}
__device__ __forceinline__ float bf2f(unsigned short h) {
  return __uint_as_float(((unsigned int)h) << 16);
}

// async global->LDS, 16 B per lane; LDS dest must be lane-contiguous
#define GLD16(g, l)                                                     \
  __builtin_amdgcn_global_load_lds(                                     \
      (__attribute__((address_space(1))) void*)(g),                     \
      (__attribute__((address_space(3))) void*)(l), 16, 0, 0)

// ---------------- row normalize ----------------
__global__ __launch_bounds__(256) void normalize_k(
    const float* __restrict__ f1, const float* __restrict__ f2,
    float* __restrict__ Yn, float* __restrict__ An) {
  int b = blockIdx.x;
  const float* src;
  float* dst;
  if (b < N) { src = f1 + (size_t)b * D; dst = Yn + (size_t)b * D; }
  else       { src = f2 + (size_t)(b - N) * D; dst = An + (size_t)(b - N) * D; }
  int tid = threadIdx.x;
  float2 e = ((const float2*)src)[tid];
  float ss = e.x * e.x + e.y * e.y;
  ss = wave_reduce(ss);
  __shared__ float sh[4];
  int lane = tid & 63, wid = tid >> 6;
  if (lane == 0) sh[wid] = ss;
  __syncthreads();
  float total = sh[0] + sh[1] + sh[2] + sh[3];
  float rn = 1.0f / sqrtf(total);
  ((float2*)dst)[tid] = make_float2(e.x * rn, e.y * rn);
}

// ---------------- fp32 NT GEMM (one-time uses: M, YAt, final P) ----------------
#define LDT 68
__global__ __launch_bounds__(256) void gemm_nt(
    const float* __restrict__ A, int lda,
    const float* __restrict__ B, int ldb,
    float* __restrict__ C, int ldc, int K) {
  __shared__ __align__(16) float At[32][LDT];
  __shared__ __align__(16) float Bt[32][LDT];
  const int tid = threadIdx.x;
  const int rowBase = blockIdx.y * 64;
  const int colBase = blockIdx.x * 64;
  const int tx = tid & 15, ty = tid >> 4;
  float acc[4][4] = {};
  const int r0 = tid >> 3;
  const int r1 = r0 + 32;
  const int kc = (tid & 7) * 4;

  for (int k0 = 0; k0 < K; k0 += 32) {
    __syncthreads();
    {
      float4 av = *(const float4*)(A + (size_t)(rowBase + r0) * lda + k0 + kc);
      At[kc + 0][r0] = av.x; At[kc + 1][r0] = av.y; At[kc + 2][r0] = av.z; At[kc + 3][r0] = av.w;
      float4 bv = *(const float4*)(B + (size_t)(colBase + r0) * ldb + k0 + kc);
      Bt[kc + 0][r0] = bv.x; Bt[kc + 1][r0] = bv.y; Bt[kc + 2][r0] = bv.z; Bt[kc + 3][r0] = bv.w;
      av = *(const float4*)(A + (size_t)(rowBase + r1) * lda + k0 + kc);
      At[kc + 0][r1] = av.x; At[kc + 1][r1] = av.y; At[kc + 2][r1] = av.z; At[kc + 3][r1] = av.w;
      bv = *(const float4*)(B + (size_t)(colBase + r1) * ldb + k0 + kc);
      Bt[kc + 0][r1] = bv.x; Bt[kc + 1][r1] = bv.y; Bt[kc + 2][r1] = bv.z; Bt[kc + 3][r1] = bv.w;
    }
    __syncthreads();
#pragma unroll
    for (int kk = 0; kk < 32; ++kk) {
      float4 a4 = *(const float4*)&At[kk][ty * 4];
      float4 b4 = *(const float4*)&Bt[kk][tx * 4];
      float a[4] = {a4.x, a4.y, a4.z, a4.w};
      float b[4] = {b4.x, b4.y, b4.z, b4.w};
#pragma unroll
      for (int r = 0; r < 4; ++r)
#pragma unroll
        for (int c = 0; c < 4; ++c) acc[r][c] = fmaf(a[r], b[c], acc[r][c]);
    }
  }
#pragma unroll
  for (int r = 0; r < 4; ++r) {
    int i = rowBase + ty * 4 + r;
    size_t off = (size_t)i * ldc + colBase + tx * 4;
    *(float4*)(C + off) = make_float4(acc[r][0], acc[r][1], acc[r][2], acc[r][3]);
  }
}

// ---------------- split fp32 -> bf16 hi/lo ----------------
__global__ __launch_bounds__(256) void split_k(const float* __restrict__ Mm,
                                               unsigned short* __restrict__ Mh,
                                               unsigned short* __restrict__ Ml) {
  int i = blockIdx.x * 256 + threadIdx.x;
  float x = Mm[i];
  unsigned short h = f2bf(x);
  Mh[i] = h;
  Ml[i] = f2bf(x - bf2f(h));
}

// ---------------- FISTA GEMM (K-split + dbuf + XCD-locality swizzle) ---------
// Computes raw partial acc of Z@M over K-half zz into Vp[zz].
// split-bf16: acc = Zh*Mh + Zh*Ml + Zl*Mh (fp32 accumulate).
// Swizzle: XCD k (heuristic: linear_id % 8) owns fixed K-half + 4 row-tiles,
// so per-XCD footprint = 512 KB (Z) + 2 MB (M) < 4 MB L2.
#define KTILES 8  // 512 / 64
__global__ __launch_bounds__(256, 2) void fista_gemm(
    const unsigned short* __restrict__ Zh, const unsigned short* __restrict__ Zl,
    const unsigned short* __restrict__ Mh, const unsigned short* __restrict__ Ml,
    float* __restrict__ Vp) {
  __shared__ __align__(16) unsigned short sAh[2][64 * 64], sAl[2][64 * 64];
  __shared__ __align__(16) unsigned short sBh[2][64 * 64], sBl[2][64 * 64];
  const int tid = threadIdx.x;
  // ---- XCD-aware remap of the 16x16x2 grid ----
  const int g = blockIdx.x + (blockIdx.y << 4) + (blockIdx.z << 8);
  const int xcd = g & 7;
  const int j = g >> 3;                       // 0..63
  const int zz = xcd & 1;                     // K-half
  const int rowTile = ((xcd >> 1) << 2) + (j >> 4);
  const int colTile = j & 15;
  const int rowBase = rowTile * 64;
  const int colBase = colTile * 64;
  const int kbase = zz * (KTILES * 64);
  const int l = tid & 63;
  const int wid = tid >> 6;
  const int wr = (wid >> 1) * 32;
  const int wc = (wid & 1) * 32;
  const int q = l >> 4, m = l & 15;

  floatx4 acc[2][2];
#pragma unroll
  for (int t = 0; t < 2; ++t)
#pragma unroll
    for (int u = 0; u < 2; ++u) acc[t][u] = (floatx4){0.f, 0.f, 0.f, 0.f};

  // staging geometry: 64 rows x 8 chunks(16B); lane-contiguous LDS,
  // XOR swizzle (chunk ^ row%8) applied on the GLOBAL side.
  const int idx0 = tid, idx1 = 256 + tid;
  const int r0 = idx0 >> 3, c0 = ((idx0 & 7) ^ (r0 & 7)) * 8;
  const int r1 = idx1 >> 3, c1 = ((idx1 & 7) ^ (r1 & 7)) * 8;
  const size_t ga0 = (size_t)(rowBase + r0) * N + c0 + kbase;
  const size_t ga1 = (size_t)(rowBase + r1) * N + c1 + kbase;
  const size_t gb0 = (size_t)(colBase + r0) * N + c0 + kbase;
  const size_t gb1 = (size_t)(colBase + r1) * N + c1 + kbase;

#define ISSUE(buf, koff)                                   \
  do {                                                     \
    GLD16(Zh + ga0 + (koff), &sAh[buf][idx0 * 8]);         \
    GLD16(Zh + ga1 + (koff), &sAh[buf][idx1 * 8]);         \
    GLD16(Zl + ga0 + (koff), &sAl[buf][idx0 * 8]);         \
    GLD16(Zl + ga1 + (koff), &sAl[buf][idx1 * 8]);         \
    GLD16(Mh + gb0 + (koff), &sBh[buf][idx0 * 8]);         \
    GLD16(Mh + gb1 + (koff), &sBh[buf][idx1 * 8]);         \
    GLD16(Ml + gb0 + (koff), &sBl[buf][idx0 * 8]);         \
    GLD16(Ml + gb1 + (koff), &sBl[buf][idx1 * 8]);         \
  } while (0)

  ISSUE(0, 0);
  __syncthreads();  // drains vmcnt -> buf 0 ready

  for (int kt = 0; kt < KTILES; ++kt) {
    const int cur = kt & 1;
    if (kt + 1 < KTILES) ISSUE(cur ^ 1, (kt + 1) * 64);  // prefetch next tile
#pragma unroll
    for (int s = 0; s < 2; ++s) {
      short8 ah[2], al[2], bh[2], bl[2];
#pragma unroll
      for (int t = 0; t < 2; ++t) {
        int ar = wr + t * 16 + m;
        int sa = ((s * 4 + q) ^ (ar & 7)) * 8;
        ah[t] = *(const short8*)&sAh[cur][ar * 64 + sa];
        al[t] = *(const short8*)&sAl[cur][ar * 64 + sa];
        int br = wc + t * 16 + m;
        int sb = ((s * 4 + q) ^ (br & 7)) * 8;
        bh[t] = *(const short8*)&sBh[cur][br * 64 + sb];
        bl[t] = *(const short8*)&sBl[cur][br * 64 + sb];
      }
#pragma unroll
      for (int t = 0; t < 2; ++t)
#pragma unroll
        for (int u = 0; u < 2; ++u) {
          acc[t][u] = __builtin_amdgcn_mfma_f32_16x16x32_bf16(ah[t], bh[u], acc[t][u], 0, 0, 0);
          acc[t][u] = __builtin_amdgcn_mfma_f32_16x16x32_bf16(ah[t], bl[u], acc[t][u], 0, 0, 0);
          acc[t][u] = __builtin_amdgcn_mfma_f32_16x16x32_bf16(al[t], bh[u], acc[t][u], 0, 0, 0);
        }
    }
    __syncthreads();  // prefetched loads have had the compute phase to land
  }
#undef ISSUE

  // epilogue: raw partial sums; C/D layout col = lane&15, row = (lane>>4)*4 + reg
  float* out = Vp + (size_t)zz * N * N;
#pragma unroll
  for (int t = 0; t < 2; ++t) {
    int rowb = rowBase + wr + t * 16 + q * 4;
#pragma unroll
    for (int u = 0; u < 2; ++u) {
      int col = colBase + wc + u * 16 + m;
#pragma unroll
      for (int r = 0; r < 4; ++r)
        out[(size_t)(rowb + r) * N + col] = acc[t][u][r];
    }
  }
}

// ---------------- matvec: w = scale * (M v) ----------------
__global__ __launch_bounds__(256) void matvec_k(
    const float* __restrict__ Mm, const float* __restrict__ v,
    float* __restrict__ w, float scale) {
  int tid = threadIdx.x;
  int lane = tid & 63, wid = tid >> 6;
  int row = blockIdx.x * 4 + wid;
  const float* mr = Mm + (size_t)row * N;
  float s = 0.0f;
#pragma unroll
  for (int j = 0; j < N; j += 64) s = fmaf(mr[j + lane], v[j + lane], s);
  s = wave_reduce(s);
  if (lane == 0) w[row] = s * scale;
}

// ---------------- Rayleigh -> step ----------------
__global__ __launch_bounds__(256) void rayleigh_k(
    const float* __restrict__ u, const float* __restrict__ w,
    float* __restrict__ stepOut) {
  int tid = threadIdx.x;
  float r1 = 0.0f, r2 = 0.0f;
  for (int j = tid; j < N; j += 256) {
    float uu = u[j];
    r1 = fmaf(uu, w[j], r1);
    r2 = fmaf(uu, uu, r2);
  }
  r1 = wave_reduce(r1);
  r2 = wave_reduce(r2);
  __shared__ float sh[8];
  int lane = tid & 63, wid = tid >> 6;
  if (lane == 0) { sh[wid] = r1; sh[4 + wid] = r2; }
  __syncthreads();
  if (tid == 0) {
    float R1 = sh[0] + sh[1] + sh[2] + sh[3];
    float R2 = sh[4] + sh[5] + sh[6] + sh[7];
    float L = 2.0f * (R1 / R2);
    stepOut[0] = 1.0f / (L + 1e-8f);
  }
}

// ---------------- init ----------------
__global__ __launch_bounds__(256) void init_k(float* __restrict__ X,
                                              unsigned short* __restrict__ Zh,
                                              unsigned short* __restrict__ Zl,
                                              float* __restrict__ v) {
  int i = blockIdx.x * 256 + threadIdx.x;
  const float c = 1.0f / (float)N;
  X[i] = c;
  Zh[i] = f2bf(c);  // 2^-10 exact in bf16
  Zl[i] = 0;
  if (i < N) v[i] = c;
}

// ---------------- combine + simplex projection (Michelot) + FISTA update ------
__global__ __launch_bounds__(256) void fista_update_k(
    const float* __restrict__ Vp0, const float* __restrict__ Vp1,
    const float* __restrict__ YAt, const float* __restrict__ stepPtr,
    float* __restrict__ X,
    unsigned short* __restrict__ Zh, unsigned short* __restrict__ Zl,
    float mom) {
  __shared__ float sh[8];
  const int r = blockIdx.x, tid = threadIdx.x;
  const int lane = tid & 63, wid = tid >> 6;
  const float c2 = 2.0f * stepPtr[0];
  float4 a0 = ((const float4*)(Vp0 + (size_t)r * N))[tid];
  float4 a1 = ((const float4*)(Vp1 + (size_t)r * N))[tid];
  float4 ya = ((const float4*)(YAt + (size_t)r * N))[tid];
  ushort4 zh4 = ((const ushort4*)(Zh + (size_t)r * N))[tid];
  ushort4 zl4 = ((const ushort4*)(Zl + (size_t)r * N))[tid];
  float vl[4];
  vl[0] = bf2f(zh4.x) + bf2f(zl4.x) - c2 * (a0.x + a1.x - ya.x);
  vl[1] = bf2f(zh4.y) + bf2f(zl4.y) - c2 * (a0.y + a1.y - ya.y);
  vl[2] = bf2f(zh4.z) + bf2f(zl4.z) - c2 * (a0.z + a1.z - ya.z);
  vl[3] = bf2f(zh4.w) + bf2f(zl4.w) - c2 * (a0.w + a1.w - ya.w);

  float s = vl[0] + vl[1] + vl[2] + vl[3];
  s = wave_reduce(s);
  if (lane == 0) sh[wid] = s;
  __syncthreads();
  float theta = (sh[0] + sh[1] + sh[2] + sh[3] - 1.0f) * (1.0f / (float)N);
  for (int it = 0; it < 40; ++it) {
    float sa = 0.0f, ka = 0.0f;
#pragma unroll
    for (int j = 0; j < 4; ++j)
      if (vl[j] > theta) { sa += vl[j]; ka += 1.0f; }
    sa = wave_reduce(sa);
    ka = wave_reduce(ka);
    __syncthreads();
    if (lane == 0) { sh[wid] = sa; sh[4 + wid] = ka; }
    __syncthreads();
    float SA = sh[0] + sh[1] + sh[2] + sh[3];
    float KA = fmaxf(sh[4] + sh[5] + sh[6] + sh[7], 1.0f);
    float tn = (SA - 1.0f) / KA;
    bool done = (tn - theta) <= (1e-7f * fabsf(tn) + 1e-12f);  // block-uniform
    theta = tn;
    if (done) break;
  }
  float4 x4 = ((const float4*)(X + (size_t)r * N))[tid];
  float xo[4] = {x4.x, x4.y, x4.z, x4.w};
  float xn[4], zn[4];
#pragma unroll
  for (int j = 0; j < 4; ++j) {
    xn[j] = fmaxf(vl[j] - theta, 0.0f);
    zn[j] = xn[j] + mom * (xn[j] - xo[j]);
  }
  ((float4*)(X + (size_t)r * N))[tid] = make_float4(xn[0], xn[1], xn[2], xn[3]);
  ushort4 zh, zl;
  zh.x = f2bf(zn[0]); zl.x = f2bf(zn[0] - bf2f(zh.x));
  zh.y = f2bf(zn[1]); zl.y = f2bf(zn[1] - bf2f(zh.y));
  zh.z = f2bf(zn[2]); zl.z = f2bf(zn[2] - bf2f(zh.z));
  zh.w = f2bf(zn[3]); zl.w = f2bf(zn[3] - bf2f(zh.w));
  ((ushort4*)(Zh + (size_t)r * N))[tid] = zh;
  ((ushort4*)(Zl + (size_t)r * N))[tid] = zl;
}

// ---------------- transpose An [N x D] -> AnT [D x N] ----------------
__global__ void transpose_k(const float* __restrict__ An, float* __restrict__ AnT) {
  __shared__ float t[32][33];
  int x = blockIdx.x * 32 + threadIdx.x;
  int y0 = blockIdx.y * 32;
#pragma unroll
  for (int j = 0; j < 32; j += 8)
    t[threadIdx.y + j][threadIdx.x] = An[(size_t)(y0 + threadIdx.y + j) * D + x];
  __syncthreads();
  int xo = y0 + threadIdx.x;
  int yo0 = blockIdx.x * 32;
#pragma unroll
  for (int j = 0; j < 32; j += 8)
    AnT[(size_t)(yo0 + threadIdx.y + j) * N + xo] = t[threadIdx.x][threadIdx.y + j];
}

// ---------------- per-row cosine ----------------
__global__ __launch_bounds__(128) void cos_k(const float* __restrict__ P,
                                             const float* __restrict__ Yn,
                                             float* __restrict__ cb) {
  int r = blockIdx.x, tid = threadIdx.x;
  float4 p = ((const float4*)(P + (size_t)r * D))[tid];
  float4 y = ((const float4*)(Yn + (size_t)r * D))[tid];
  float d  = p.x * y.x + p.y * y.y + p.z * y.z + p.w * y.w;
  float np = p.x * p.x + p.y * p.y + p.z * p.z + p.w * p.w;
  float ny = y.x * y.x + y.y * y.y + y.z * y.z + y.w * y.w;
  d = wave_reduce(d);
  np = wave_reduce(np);
  ny = wave_reduce(ny);
  __shared__ float sh[6];
  int lane = tid & 63, wid = tid >> 6;
  if (lane == 0) { sh[wid] = d; sh[2 + wid] = np; sh[4 + wid] = ny; }
  __syncthreads();
  if (tid == 0) {
    float dt = sh[0] + sh[1], npt = sh[2] + sh[3], nyt = sh[4] + sh[5];
    cb[r] = dt / (fmaxf(sqrtf(npt), 1e-8f) * fmaxf(sqrtf(nyt), 1e-8f));
  }
}

// ---------------- mean ----------------
__global__ __launch_bounds__(256) void mean_k(const float* __restrict__ cb,
                                              float* __restrict__ out) {
  int tid = threadIdx.x;
  float s = cb[tid] + cb[tid + 256] + cb[tid + 512] + cb[tid + 768];
  s = wave_reduce(s);
  __shared__ float sh[4];
  int lane = tid & 63, wid = tid >> 6;
  if (lane == 0) sh[wid] = s;
  __syncthreads();
  if (tid == 0) out[0] = (sh[0] + sh[1] + sh[2] + sh[3]) * (1.0f / (float)N);
}

// ---------------- host orchestration ----------------
extern "C" void kernel_launch(void* const* d_in, const int* in_sizes, int n_in,
                              void* d_out, int out_size, void* d_ws, size_t ws_size,
                              hipStream_t stream) {
  const float* fea1 = (const float*)d_in[0];
  const float* fea2 = (const float*)d_in[1];
  float* ws = (float*)d_ws;
  float* Yn  = ws;                              // N*D
  float* An  = Yn + (size_t)N * D;              // N*D
  float* Mm  = An + (size_t)N * D;              // N*N
  float* YAt = Mm + (size_t)N * N;              // N*N
  float* X   = YAt + (size_t)N * N;             // N*N
  float* Vp0 = X + (size_t)N * N;               // N*N
  float* Vp1 = Vp0 + (size_t)N * N;             // N*N
  unsigned short* Zh = (unsigned short*)(Vp1 + (size_t)N * N);  // N*N bf16
  unsigned short* Zl = Zh + (size_t)N * N;
  unsigned short* Mh = Zl + (size_t)N * N;
  unsigned short* Ml = Mh + (size_t)N * N;
  float* vp   = (float*)(Ml + (size_t)N * N);
  float* wp   = vp + N;
  float* stepP = wp + N;
  // dead-buffer reuse after the FISTA loop:
  float* AnT = Vp0;                     // D*N
  float* P   = Vp0 + (size_t)N * D;     // N*D
  float* cosb = Mm;

  normalize_k<<<2 * N, 256, 0, stream>>>(fea1, fea2, Yn, An);
  gemm_nt<<<dim3(N / 64, N / 64), 256, 0, stream>>>(An, D, An, D, Mm, N, D);
  gemm_nt<<<dim3(N / 64, N / 64), 256, 0, stream>>>(Yn, D, An, D, YAt, N, D);
  split_k<<<(N * N) / 256, 256, 0, stream>>>(Mm, Mh, Ml);
  init_k<<<(N * N) / 256, 256, 0, stream>>>(X, Zh, Zl, vp);

  float* pv = vp;
  float* pw = wp;
  for (int i = 0; i < PIT; ++i) {
    matvec_k<<<N / 4, 256, 0, stream>>>(Mm, pv, pw, 0.125f);
    float* t = pv; pv = pw; pw = t;
  }
  matvec_k<<<N / 4, 256, 0, stream>>>(Mm, pv, pw, 1.0f);
  rayleigh_k<<<1, 256, 0, stream>>>(pv, pw, stepP);

  float t = 1.0f;
  for (int it = 0; it < NIT; ++it) {
    fista_gemm<<<dim3(N / 64, N / 64, 2), 256, 0, stream>>>(Zh, Zl, Mh, Ml, Vp0);
    float tn = 0.5f * (1.0f + sqrtf(1.0f + 4.0f * t * t));
    float mom = (t - 1.0f) / tn;
    t = tn;
    fista_update_k<<<N, 256, 0, stream>>>(Vp0, Vp1, YAt, stepP, X, Zh, Zl, mom);
  }

  transpose_k<<<dim3(D / 32, N / 32), dim3(32, 8), 0, stream>>>(An, AnT);
  gemm_nt<<<dim3(D / 64, N / 64), 256, 0, stream>>>(X, N, AnT, N, P, D, N);
  cos_k<<<N, 128, 0, stream>>>(P, Yn, cosb);
  mean_k<<<1, 256, 0, stream>>>(cosb, (float*)d_out);
}